// Round 6
// baseline (5729.702 us; speedup 1.0000x reference)
//
#include <hip/hip_runtime.h>

#define BS   256
#define KIN  8000
#define HID  1024
#define TST  100
#define ACTD 32
#define OUTD 64
#define KTOT 1056            // 1024 (Wh) + 32 (Wi) concatenated K

typedef __attribute__((ext_vector_type(8))) _Float16 f16x8;
typedef __attribute__((ext_vector_type(4))) float f32x4;
typedef unsigned short u16;
typedef unsigned int   u32;

__device__ __forceinline__ u16 f2h(float f) {
    union { _Float16 h; u16 u; } c;
    c.h = (_Float16)f;             // v_cvt_f16_f32, RNE
    return c.u;
}
__device__ __forceinline__ float sigm(float x) { return 1.0f / (1.0f + __expf(-x)); }

#define MFMA16(a, b, c) __builtin_amdgcn_mfma_f32_16x16x32_f16(a, b, c, 0, 0, 0)

// ---------------- P1: WfT[c][k] = fp16(Wh[k][c] | Wi[k-1024][c]) ----------------
__global__ __launch_bounds__(256) void k_prep_w(const float* __restrict__ Wh,
                                                const float* __restrict__ Wi,
                                                u16* __restrict__ Wf) {
    __shared__ float T[32][33];
    const int k0 = blockIdx.x * 32;      // 33 tiles cover k=0..1055
    const int c0 = blockIdx.y * 32;
    const int tid = threadIdx.x;
    {
        int k = tid >> 3, c4 = (tid & 7) * 4;
        int kk = k0 + k;
        const float* src = (kk < HID) ? (Wh + (size_t)kk * 3072 + c0 + c4)
                                      : (Wi + (size_t)(kk - HID) * 3072 + c0 + c4);
        float4 v = *(const float4*)src;
        T[k][c4 + 0] = v.x; T[k][c4 + 1] = v.y; T[k][c4 + 2] = v.z; T[k][c4 + 3] = v.w;
    }
    __syncthreads();
    {
        int c = tid >> 3, k4 = (tid & 7) * 4;
        size_t base = (size_t)(c0 + c) * KTOT + k0 + k4;
#pragma unroll
        for (int j = 0; j < 4; j++) Wf[base + j] = f2h(T[k4 + j][c]);
    }
}

// ---------------- P2: WoT[n][k] = fp16(Wo[k][n]) ----------------
__global__ __launch_bounds__(256) void k_prep_wo(const float* __restrict__ Wo,
                                                 u16* __restrict__ WoT) {
    int idx = blockIdx.x * 256 + threadIdx.x;   // 65536
    int n = idx & 63, k = idx >> 6;
    WoT[(size_t)n * HID + k] = f2h(Wo[(size_t)k * OUTD + n]);
}

// ---------------- P3: action fp32 -> fp16 (layout preserved) ----------------
__global__ __launch_bounds__(256) void k_prep_act(const float* __restrict__ act,
                                                  u16* __restrict__ acth) {
    int i = (blockIdx.x * 256 + threadIdx.x) * 4;
    float4 v = *(const float4*)(act + i);
    ushort4 h = make_ushort4(f2h(v.x), f2h(v.y), f2h(v.z), f2h(v.w));
    *(ushort4*)(acth + i) = h;
}

// ---------------- h0 partial GEMM (fp32, split-K) ----------------
#define H0_SPLIT 10
#define H0_KC    800
__global__ __launch_bounds__(256) void k_h0(const float* __restrict__ x,
                                            const float* __restrict__ Win,
                                            float* __restrict__ part) {
    __shared__ float As[32][33];   // [k][m]
    __shared__ float Bs[32][68];   // [k][n]
    const int n0 = blockIdx.x * 64, m0 = blockIdx.y * 32, s = blockIdx.z;
    const int tid = threadIdx.x;
    const int tm = tid >> 4, tn = tid & 15;
    float acc[2][4] = {};

    const int ar = tid >> 3, ac4 = (tid & 7) * 4;
    int br[2], bn4[2];
#pragma unroll
    for (int i = 0; i < 2; i++) { int e = tid + 256 * i; br[i] = e >> 4; bn4[i] = (e & 15) * 4; }
    const int k0 = s * H0_KC;

    float4 aReg = *(const float4*)(x + (size_t)(m0 + ar) * KIN + k0 + ac4);
    float4 bReg0 = *(const float4*)(Win + (size_t)(k0 + br[0]) * HID + n0 + bn4[0]);
    float4 bReg1 = *(const float4*)(Win + (size_t)(k0 + br[1]) * HID + n0 + bn4[1]);

    for (int it = 0; it < 25; it++) {
        __syncthreads();
        As[ac4 + 0][ar] = aReg.x; As[ac4 + 1][ar] = aReg.y;
        As[ac4 + 2][ar] = aReg.z; As[ac4 + 3][ar] = aReg.w;
        *(float4*)&Bs[br[0]][bn4[0]] = bReg0;
        *(float4*)&Bs[br[1]][bn4[1]] = bReg1;
        if (it < 24) {
            int kn = k0 + (it + 1) * 32;
            aReg  = *(const float4*)(x + (size_t)(m0 + ar) * KIN + kn + ac4);
            bReg0 = *(const float4*)(Win + (size_t)(kn + br[0]) * HID + n0 + bn4[0]);
            bReg1 = *(const float4*)(Win + (size_t)(kn + br[1]) * HID + n0 + bn4[1]);
        }
        __syncthreads();
#pragma unroll
        for (int kk = 0; kk < 32; kk++) {
            float a0 = As[kk][tm * 2], a1 = As[kk][tm * 2 + 1];
            float4 b = *(float4*)&Bs[kk][tn * 4];
            acc[0][0] = fmaf(a0, b.x, acc[0][0]); acc[0][1] = fmaf(a0, b.y, acc[0][1]);
            acc[0][2] = fmaf(a0, b.z, acc[0][2]); acc[0][3] = fmaf(a0, b.w, acc[0][3]);
            acc[1][0] = fmaf(a1, b.x, acc[1][0]); acc[1][1] = fmaf(a1, b.y, acc[1][1]);
            acc[1][2] = fmaf(a1, b.z, acc[1][2]); acc[1][3] = fmaf(a1, b.w, acc[1][3]);
        }
    }
    float* dst = part + (size_t)s * (BS * HID);
#pragma unroll
    for (int i = 0; i < 2; i++) {
        float4 v = make_float4(acc[i][0], acc[i][1], acc[i][2], acc[i][3]);
        *(float4*)(dst + (size_t)(m0 + tm * 2 + i) * HID + n0 + tn * 4) = v;
    }
}

__global__ __launch_bounds__(256) void k_h0red(const float* __restrict__ part,
                                               const float* __restrict__ b_in,
                                               float* __restrict__ h0,
                                               u16* __restrict__ h0h) {
    int idx = (blockIdx.x * 256 + threadIdx.x) * 4;
    float4 sv = *(const float4*)(part + idx);
#pragma unroll
    for (int p = 1; p < H0_SPLIT; p++) {
        float4 v = *(const float4*)(part + (size_t)p * (BS * HID) + idx);
        sv.x += v.x; sv.y += v.y; sv.z += v.z; sv.w += v.w;
    }
    int n = idx & (HID - 1);
    float4 b = *(const float4*)(b_in + n);
    sv.x = fmaxf(sv.x + b.x, 0.f); sv.y = fmaxf(sv.y + b.y, 0.f);
    sv.z = fmaxf(sv.z + b.z, 0.f); sv.w = fmaxf(sv.w + b.w, 0.f);
    *(float4*)(h0 + idx) = sv;
    *(ushort4*)(h0h + idx) = make_ushort4(f2h(sv.x), f2h(sv.y), f2h(sv.z), f2h(sv.w));
}

// ---------------- persistent GRU: all 100 steps in one cooperative launch ----------------
// 256 blocks x 512 thr. Block = (j-tile 16 cols) x (b-tile 64 rows); bx = jt*4+bt.
// Weights (3 gates x 16 j x 1056 k fp16 = 102 KB) staged in LDS ONCE, reused 100 steps.
// Waves: bsup (2 x 32 rows) x kq (4 k-groups: 288/256/256/256, last 32 = action).
// A (h fp16) loaded global->VGPR directly in MFMA layout; no K-loop barriers.
// h fp32 ping-pong lives in the home (kq=0) waves' registers.
__global__ __launch_bounds__(512, 2) void k_gru(const u16* __restrict__ h0h,
                                                const float* __restrict__ h0f,
                                                const u16* __restrict__ acth,
                                                const u16* __restrict__ Wf,
                                                const float* __restrict__ bi,
                                                const float* __restrict__ bhn,
                                                u16* __restrict__ outs,
                                                u32* __restrict__ bar) {
    __shared__ u16 Wlds[3][16][1064];          // pitch 1064 halfs: j-stride 532 dw = 2-way (free)
    __shared__ float RED[2][3][2][64][18];     // [bsup][kq-1][sub][lane][16 slots, pad 18]

    const int tid = threadIdx.x;
    const int bx = blockIdx.x;
    const int j0 = (bx >> 2) * 16;
    const int b0 = (bx & 3) * 64;
    const int w = tid >> 6;
    const int bsup = w >> 2, kq = w & 3;
    const int lane = tid & 63;
    const int m16 = lane & 15, quad = lane >> 4;

    // ---- stage weight slice to LDS (once) ----
    for (int p = 0; p < 13; p++) {
        int c = tid + p * 512;                 // 6336 chunks of 8 halfs
        if (c < 6336) {
            int row = c / 132, kc = (c % 132) * 8;
            int g = row >> 4, jj = row & 15;
            int4 v = *(const int4*)(const void*)(Wf + (size_t)(g * HID + j0 + jj) * KTOT + kc);
            *(int4*)(void*)&Wlds[g][jj][kc] = v;
        }
    }

    // home-wave persistent state
    const int j = j0 + m16;
    float bir = 0, biz = 0, bin_ = 0, bh_ = 0;
    float hreg[2][4] = {};
    if (kq == 0) {
        bir = bi[j]; biz = bi[HID + j]; bin_ = bi[2 * HID + j]; bh_ = bhn[j];
#pragma unroll
        for (int sub = 0; sub < 2; sub++)
#pragma unroll
            for (int rg = 0; rg < 4; rg++)
                hreg[sub][rg] = h0f[(size_t)(b0 + bsup * 32 + sub * 16 + quad * 4 + rg) * HID + j];
    }
    __syncthreads();

    const int kst = kq * 256 + (kq ? 32 : 0);  // {0,288,544,800}
    const int iters = kq ? 8 : 9;
    const int koff = quad * 8;
    const int row0 = b0 + bsup * 32 + m16;     // A-operand row (sub 0)

    for (int t = 0; t < TST; t++) {
        const u16* Asrc = t ? (outs + (size_t)(t - 1) * BS * HID) : h0h;
        const u16* arow0 = Asrc + (size_t)row0 * HID;
        const u16* arow1 = arow0 + 16 * HID;
        const u16* actp0 = acth + (size_t)row0 * (TST * ACTD) + t * ACTD + koff;
        const u16* actp1 = actp0 + 16 * (TST * ACTD);

        f32x4 aR[2] = {{0,0,0,0},{0,0,0,0}}, aZ[2] = {{0,0,0,0},{0,0,0,0}};
        f32x4 aN[2] = {{0,0,0,0},{0,0,0,0}}, aI[2] = {{0,0,0,0},{0,0,0,0}};

#pragma unroll
        for (int kt = 0; kt < 9; kt++) {
            if (kt < iters) {
                const int k = kst + kt * 32 + koff;
                f16x8 a0, a1;
                if (kq == 3 && kt == 7) {      // action block (k 1024..1056)
                    a0 = *(const f16x8*)(const void*)actp0;
                    a1 = *(const f16x8*)(const void*)actp1;
                } else {
                    a0 = *(const f16x8*)(const void*)(arow0 + k);
                    a1 = *(const f16x8*)(const void*)(arow1 + k);
                }
                f16x8 wr = *(const f16x8*)&Wlds[0][m16][kst + kt * 32 + koff];
                f16x8 wz = *(const f16x8*)&Wlds[1][m16][kst + kt * 32 + koff];
                f16x8 wn = *(const f16x8*)&Wlds[2][m16][kst + kt * 32 + koff];
                aR[0] = MFMA16(a0, wr, aR[0]);  aR[1] = MFMA16(a1, wr, aR[1]);
                aZ[0] = MFMA16(a0, wz, aZ[0]);  aZ[1] = MFMA16(a1, wz, aZ[1]);
                if (kq == 3 && kt == 7) {
                    aI[0] = MFMA16(a0, wn, aI[0]);  aI[1] = MFMA16(a1, wn, aI[1]);
                } else {
                    aN[0] = MFMA16(a0, wn, aN[0]);  aN[1] = MFMA16(a1, wn, aN[1]);
                }
            }
        }

        if (kq != 0) {
#pragma unroll
            for (int sub = 0; sub < 2; sub++) {
                float* d = &RED[bsup][kq - 1][sub][lane][0];
                *(float2*)(d + 0)  = make_float2(aR[sub][0], aR[sub][1]);
                *(float2*)(d + 2)  = make_float2(aR[sub][2], aR[sub][3]);
                *(float2*)(d + 4)  = make_float2(aZ[sub][0], aZ[sub][1]);
                *(float2*)(d + 6)  = make_float2(aZ[sub][2], aZ[sub][3]);
                *(float2*)(d + 8)  = make_float2(aN[sub][0], aN[sub][1]);
                *(float2*)(d + 10) = make_float2(aN[sub][2], aN[sub][3]);
                *(float2*)(d + 12) = make_float2(aI[sub][0], aI[sub][1]);
                *(float2*)(d + 14) = make_float2(aI[sub][2], aI[sub][3]);
            }
        }
        __syncthreads();
        if (kq == 0) {
            u16* orow = outs + (size_t)t * BS * HID;
#pragma unroll
            for (int sub = 0; sub < 2; sub++) {
                float R[4], Z[4], N[4], I[4];
#pragma unroll
                for (int rg = 0; rg < 4; rg++) {
                    R[rg] = aR[sub][rg]; Z[rg] = aZ[sub][rg];
                    N[rg] = aN[sub][rg]; I[rg] = aI[sub][rg];
                }
#pragma unroll
                for (int src = 0; src < 3; src++) {
                    const float* d = &RED[bsup][src][sub][lane][0];
#pragma unroll
                    for (int rg = 0; rg < 4; rg++) {
                        R[rg] += d[rg]; Z[rg] += d[4 + rg];
                        N[rg] += d[8 + rg]; I[rg] += d[12 + rg];
                    }
                }
#pragma unroll
                for (int rg = 0; rg < 4; rg++) {
                    float r = sigm(R[rg] + bir);
                    float z = sigm(Z[rg] + biz);
                    float n = tanhf(I[rg] + bin_ + r * (N[rg] + bh_));
                    float hnew = (1.0f - z) * n + z * hreg[sub][rg];
                    hreg[sub][rg] = hnew;
                    orow[(size_t)(b0 + bsup * 32 + sub * 16 + quad * 4 + rg) * HID + j] = f2h(hnew);
                }
            }
        }

        // ---- grid barrier (monotonic counter, agent-scope fences) ----
        __builtin_amdgcn_fence(__ATOMIC_RELEASE, "agent");
        __syncthreads();
        if (tid == 0) {
            __hip_atomic_fetch_add(bar, 1u, __ATOMIC_ACQ_REL, __HIP_MEMORY_SCOPE_AGENT);
            u32 tgt = 256u * (u32)(t + 1);
            while (__hip_atomic_load(bar, __ATOMIC_ACQUIRE, __HIP_MEMORY_SCOPE_AGENT) < tgt)
                __builtin_amdgcn_s_sleep(4);
        }
        __syncthreads();
        __builtin_amdgcn_fence(__ATOMIC_ACQUIRE, "agent");
    }
}

// ---------------- k_out: out = outs(fp16) @ Wo + bo, MFMA ----------------
__global__ __launch_bounds__(256) void k_out(const u16* __restrict__ outs,
                                             const u16* __restrict__ WoT,
                                             const float* __restrict__ bo,
                                             float* __restrict__ out) {
    __shared__ u16 As[64][40], Bs[64][40];
    const int tid = threadIdx.x;
    const int m0 = blockIdx.x * 64;
    const int w = tid >> 6, lane = tid & 63;
    const int m16 = lane & 15, quad = lane >> 4;
    f32x4 acc[4] = {{0,0,0,0},{0,0,0,0},{0,0,0,0},{0,0,0,0}};

    const int ar = tid >> 2, aq = tid & 3;
    const u16* aptr = outs + (size_t)(m0 + ar) * HID + aq * 8;
    const u16* bptr = WoT + (size_t)ar * HID + aq * 8;
    int4 aR = *(const int4*)(const void*)aptr;
    int4 bR = *(const int4*)(const void*)bptr;

    for (int kt = 0; kt < 32; kt++) {
        __syncthreads();
        *(int4*)(void*)&As[ar][aq * 8] = aR;
        *(int4*)(void*)&Bs[ar][aq * 8] = bR;
        if (kt < 31) {
            aR = *(const int4*)(const void*)(aptr + (kt + 1) * 32);
            bR = *(const int4*)(const void*)(bptr + (kt + 1) * 32);
        }
        __syncthreads();
        f16x8 a = *(const f16x8*)&As[w * 16 + m16][quad * 8];
#pragma unroll
        for (int nt = 0; nt < 4; nt++) {
            f16x8 b = *(const f16x8*)&Bs[nt * 16 + m16][quad * 8];
            acc[nt] = __builtin_amdgcn_mfma_f32_16x16x32_f16(a, b, acc[nt], 0, 0, 0);
        }
    }
    const int mbase = m0 + w * 16 + quad * 4;
#pragma unroll
    for (int nt = 0; nt < 4; nt++) {
        int n = nt * 16 + m16;
        float bov = bo[n];
#pragma unroll
        for (int rg = 0; rg < 4; rg++) {
            int m = mbase + rg;
            int b = m & 255, t = m >> 8;
            out[((size_t)b * TST + t) * OUTD + n] = acc[nt][rg] + bov;
        }
    }
}

extern "C" void kernel_launch(void* const* d_in, const int* in_sizes, int n_in,
                              void* d_out, int out_size, void* d_ws, size_t ws_size,
                              hipStream_t stream) {
    const float* history = (const float*)d_in[0];
    const float* action  = (const float*)d_in[1];
    const float* W_in    = (const float*)d_in[2];
    const float* b_in    = (const float*)d_in[3];
    const float* Wi      = (const float*)d_in[4];
    const float* bi      = (const float*)d_in[5];
    const float* Wh      = (const float*)d_in[6];
    const float* bhn     = (const float*)d_in[7];
    const float* Wo      = (const float*)d_in[8];
    const float* bo      = (const float*)d_in[9];
    float* out = (float*)d_out;

    char* ws = (char*)d_ws;
    float* hbuf0 = (float*)(ws + 0);                    // 1 MB (fp32 h0)
    u16*   h0h   = (u16*)  (ws + (2u << 20));           // 0.5 MB (fp16 h0)
    u16*   Wf    = (u16*)  (ws + (3u << 20));           // 6.33 MB
    u16*   WoT   = (u16*)  (ws + (10u << 20));          // 128 KB
    u16*   acth  = (u16*)  (ws + (11u << 20));          // 1.6 MB
    float* part  = (float*)(ws + (13u << 20));          // 10 MB (13..23 MiB)
    u32*   bar   = (u32*)  (ws + (23u << 20));          // 64 B barrier counter
    u16*   outsb = (u16*)  (ws + (24u << 20));          // 52.4 MB

    (void)hipMemsetAsync(bar, 0, 64, stream);
    k_prep_w<<<dim3(33, 96), 256, 0, stream>>>(Wh, Wi, Wf);
    k_prep_wo<<<256, 256, 0, stream>>>(Wo, WoT);
    k_prep_act<<<800, 256, 0, stream>>>(action, acth);
    k_h0<<<dim3(16, 8, H0_SPLIT), 256, 0, stream>>>(history, W_in, part);
    k_h0red<<<256, 256, 0, stream>>>(part, b_in, hbuf0, h0h);

    {
        const u16* a0 = h0h; const float* a1 = hbuf0; const u16* a2 = acth;
        const u16* a3 = Wf;  const float* a4 = bi;    const float* a5 = bhn;
        u16* a6 = outsb;     u32* a7 = bar;
        void* args[] = {(void*)&a0, (void*)&a1, (void*)&a2, (void*)&a3,
                        (void*)&a4, (void*)&a5, (void*)&a6, (void*)&a7};
        (void)hipLaunchCooperativeKernel((const void*)k_gru, dim3(256), dim3(512),
                                         args, 0, stream);
    }

    k_out<<<400, 256, 0, stream>>>(outsb, WoT, bo, out);
}

// Round 7
// 1635.024 us; speedup vs baseline: 3.5044x; 3.5044x over previous
//
#include <hip/hip_runtime.h>

#define BS   256
#define KIN  8000
#define HID  1024
#define TST  100
#define ACTD 32
#define OUTD 64
#define KTOT 1056            // 1024 (Wh) + 32 (Wi) concatenated K

typedef __attribute__((ext_vector_type(8))) _Float16 f16x8;
typedef __attribute__((ext_vector_type(4))) float f32x4;
typedef unsigned short u16;
typedef unsigned int   u32;
typedef unsigned long long u64;

__device__ __forceinline__ u16 f2h(float f) {
    union { _Float16 h; u16 u; } c;
    c.h = (_Float16)f;             // v_cvt_f16_f32, RNE
    return c.u;
}
__device__ __forceinline__ float sigm(float x) { return 1.0f / (1.0f + __expf(-x)); }

#define MFMA16(a, b, c) __builtin_amdgcn_mfma_f32_16x16x32_f16(a, b, c, 0, 0, 0)

// Memory-side coherent load: 16B fragment as two relaxed agent-scope u64 atomics
// (bypass L1/L2, served by Infinity Cache -- no fences/invalidation needed).
__device__ __forceinline__ f16x8 aload(const u16* p) {
    union { u64 d[2]; f16x8 v; } u;
    const u64* q = (const u64*)(const void*)p;
    u.d[0] = __hip_atomic_load(q + 0, __ATOMIC_RELAXED, __HIP_MEMORY_SCOPE_AGENT);
    u.d[1] = __hip_atomic_load(q + 1, __ATOMIC_RELAXED, __HIP_MEMORY_SCOPE_AGENT);
    return u.v;
}

// ---------------- P1: WfT[c][k] = fp16(Wh[k][c] | Wi[k-1024][c]) ----------------
__global__ __launch_bounds__(256) void k_prep_w(const float* __restrict__ Wh,
                                                const float* __restrict__ Wi,
                                                u16* __restrict__ Wf) {
    __shared__ float T[32][33];
    const int k0 = blockIdx.x * 32;      // 33 tiles cover k=0..1055
    const int c0 = blockIdx.y * 32;
    const int tid = threadIdx.x;
    {
        int k = tid >> 3, c4 = (tid & 7) * 4;
        int kk = k0 + k;
        const float* src = (kk < HID) ? (Wh + (size_t)kk * 3072 + c0 + c4)
                                      : (Wi + (size_t)(kk - HID) * 3072 + c0 + c4);
        float4 v = *(const float4*)src;
        T[k][c4 + 0] = v.x; T[k][c4 + 1] = v.y; T[k][c4 + 2] = v.z; T[k][c4 + 3] = v.w;
    }
    __syncthreads();
    {
        int c = tid >> 3, k4 = (tid & 7) * 4;
        size_t base = (size_t)(c0 + c) * KTOT + k0 + k4;
#pragma unroll
        for (int j = 0; j < 4; j++) Wf[base + j] = f2h(T[k4 + j][c]);
    }
}

// ---------------- P2: WoT[n][k] = fp16(Wo[k][n]) ----------------
__global__ __launch_bounds__(256) void k_prep_wo(const float* __restrict__ Wo,
                                                 u16* __restrict__ WoT) {
    int idx = blockIdx.x * 256 + threadIdx.x;   // 65536
    int n = idx & 63, k = idx >> 6;
    WoT[(size_t)n * HID + k] = f2h(Wo[(size_t)k * OUTD + n]);
}

// ---------------- P3: action fp32 -> fp16 (layout preserved) ----------------
__global__ __launch_bounds__(256) void k_prep_act(const float* __restrict__ act,
                                                  u16* __restrict__ acth) {
    int i = (blockIdx.x * 256 + threadIdx.x) * 4;
    float4 v = *(const float4*)(act + i);
    ushort4 h = make_ushort4(f2h(v.x), f2h(v.y), f2h(v.z), f2h(v.w));
    *(ushort4*)(acth + i) = h;
}

// ---------------- h0 partial GEMM (fp32, split-K) ----------------
#define H0_SPLIT 10
#define H0_KC    800
__global__ __launch_bounds__(256) void k_h0(const float* __restrict__ x,
                                            const float* __restrict__ Win,
                                            float* __restrict__ part) {
    __shared__ float As[32][33];   // [k][m]
    __shared__ float Bs[32][68];   // [k][n]
    const int n0 = blockIdx.x * 64, m0 = blockIdx.y * 32, s = blockIdx.z;
    const int tid = threadIdx.x;
    const int tm = tid >> 4, tn = tid & 15;
    float acc[2][4] = {};

    const int ar = tid >> 3, ac4 = (tid & 7) * 4;
    int br[2], bn4[2];
#pragma unroll
    for (int i = 0; i < 2; i++) { int e = tid + 256 * i; br[i] = e >> 4; bn4[i] = (e & 15) * 4; }
    const int k0 = s * H0_KC;

    float4 aReg = *(const float4*)(x + (size_t)(m0 + ar) * KIN + k0 + ac4);
    float4 bReg0 = *(const float4*)(Win + (size_t)(k0 + br[0]) * HID + n0 + bn4[0]);
    float4 bReg1 = *(const float4*)(Win + (size_t)(k0 + br[1]) * HID + n0 + bn4[1]);

    for (int it = 0; it < 25; it++) {
        __syncthreads();
        As[ac4 + 0][ar] = aReg.x; As[ac4 + 1][ar] = aReg.y;
        As[ac4 + 2][ar] = aReg.z; As[ac4 + 3][ar] = aReg.w;
        *(float4*)&Bs[br[0]][bn4[0]] = bReg0;
        *(float4*)&Bs[br[1]][bn4[1]] = bReg1;
        if (it < 24) {
            int kn = k0 + (it + 1) * 32;
            aReg  = *(const float4*)(x + (size_t)(m0 + ar) * KIN + kn + ac4);
            bReg0 = *(const float4*)(Win + (size_t)(kn + br[0]) * HID + n0 + bn4[0]);
            bReg1 = *(const float4*)(Win + (size_t)(kn + br[1]) * HID + n0 + bn4[1]);
        }
        __syncthreads();
#pragma unroll
        for (int kk = 0; kk < 32; kk++) {
            float a0 = As[kk][tm * 2], a1 = As[kk][tm * 2 + 1];
            float4 b = *(float4*)&Bs[kk][tn * 4];
            acc[0][0] = fmaf(a0, b.x, acc[0][0]); acc[0][1] = fmaf(a0, b.y, acc[0][1]);
            acc[0][2] = fmaf(a0, b.z, acc[0][2]); acc[0][3] = fmaf(a0, b.w, acc[0][3]);
            acc[1][0] = fmaf(a1, b.x, acc[1][0]); acc[1][1] = fmaf(a1, b.y, acc[1][1]);
            acc[1][2] = fmaf(a1, b.z, acc[1][2]); acc[1][3] = fmaf(a1, b.w, acc[1][3]);
        }
    }
    float* dst = part + (size_t)s * (BS * HID);
#pragma unroll
    for (int i = 0; i < 2; i++) {
        float4 v = make_float4(acc[i][0], acc[i][1], acc[i][2], acc[i][3]);
        *(float4*)(dst + (size_t)(m0 + tm * 2 + i) * HID + n0 + tn * 4) = v;
    }
}

__global__ __launch_bounds__(256) void k_h0red(const float* __restrict__ part,
                                               const float* __restrict__ b_in,
                                               float* __restrict__ h0,
                                               u16* __restrict__ h0h) {
    int idx = (blockIdx.x * 256 + threadIdx.x) * 4;
    float4 sv = *(const float4*)(part + idx);
#pragma unroll
    for (int p = 1; p < H0_SPLIT; p++) {
        float4 v = *(const float4*)(part + (size_t)p * (BS * HID) + idx);
        sv.x += v.x; sv.y += v.y; sv.z += v.z; sv.w += v.w;
    }
    int n = idx & (HID - 1);
    float4 b = *(const float4*)(b_in + n);
    sv.x = fmaxf(sv.x + b.x, 0.f); sv.y = fmaxf(sv.y + b.y, 0.f);
    sv.z = fmaxf(sv.z + b.z, 0.f); sv.w = fmaxf(sv.w + b.w, 0.f);
    *(float4*)(h0 + idx) = sv;
    *(ushort4*)(h0h + idx) = make_ushort4(f2h(sv.x), f2h(sv.y), f2h(sv.z), f2h(sv.w));
}

// ---------------- persistent GRU: all 100 steps in one cooperative launch ----------------
// 256 blocks x 512 thr. Block = (j-tile 16 cols) x (b-tile 64 rows).
// Weights (102 KB) staged in LDS ONCE, reused 100 steps.
// Cross-step h exchange via MEMORY-SIDE relaxed agent atomics (stores u16,
// loads u64x2) -- coherent at the Infinity Cache with ZERO fences/invalidates.
// Grid barrier: relaxed add + relaxed polls, ordering by s_waitcnt(0)+syncthreads
// (stores IC-acked at vmcnt==0 before the signal).
__global__ __launch_bounds__(512, 2) void k_gru(const u16* __restrict__ h0h,
                                                const float* __restrict__ h0f,
                                                const u16* __restrict__ acth,
                                                const u16* __restrict__ Wf,
                                                const float* __restrict__ bi,
                                                const float* __restrict__ bhn,
                                                u16* __restrict__ outs,
                                                u32* __restrict__ bar) {
    __shared__ u16 Wlds[3][16][1064];          // pitch 1064 halfs
    __shared__ float RED[2][3][2][64][18];     // [bsup][kq-1][sub][lane][16 slots, pad 18]

    const int tid = threadIdx.x;
    const int bx = blockIdx.x;
    const int j0 = (bx >> 2) * 16;
    const int b0 = (bx & 3) * 64;
    const int w = tid >> 6;
    const int bsup = w >> 2, kq = w & 3;
    const int lane = tid & 63;
    const int m16 = lane & 15, quad = lane >> 4;

    // ---- stage weight slice to LDS (once) ----
    for (int p = 0; p < 13; p++) {
        int c = tid + p * 512;                 // 6336 chunks of 8 halfs
        if (c < 6336) {
            int row = c / 132, kc = (c % 132) * 8;
            int g = row >> 4, jj = row & 15;
            int4 v = *(const int4*)(const void*)(Wf + (size_t)(g * HID + j0 + jj) * KTOT + kc);
            *(int4*)(void*)&Wlds[g][jj][kc] = v;
        }
    }

    // home-wave persistent state
    const int j = j0 + m16;
    float bir = 0, biz = 0, bin_ = 0, bh_ = 0;
    float hreg[2][4] = {};
    if (kq == 0) {
        bir = bi[j]; biz = bi[HID + j]; bin_ = bi[2 * HID + j]; bh_ = bhn[j];
#pragma unroll
        for (int sub = 0; sub < 2; sub++)
#pragma unroll
            for (int rg = 0; rg < 4; rg++)
                hreg[sub][rg] = h0f[(size_t)(b0 + bsup * 32 + sub * 16 + quad * 4 + rg) * HID + j];
    }
    __syncthreads();

    const int kst = kq * 256 + (kq ? 32 : 0);  // {0,288,544,800}
    const int iters = kq ? 8 : 9;
    const int koff = quad * 8;
    const int row0 = b0 + bsup * 32 + m16;     // A-operand row (sub 0)

    for (int t = 0; t < TST; t++) {
        const u16* Asrc = t ? (outs + (size_t)(t - 1) * BS * HID) : h0h;
        const u16* arow0 = Asrc + (size_t)row0 * HID;
        const u16* arow1 = arow0 + 16 * HID;
        const u16* actp0 = acth + (size_t)row0 * (TST * ACTD) + t * ACTD + koff;
        const u16* actp1 = actp0 + 16 * (TST * ACTD);

        f32x4 aR[2] = {{0,0,0,0},{0,0,0,0}}, aZ[2] = {{0,0,0,0},{0,0,0,0}};
        f32x4 aN[2] = {{0,0,0,0},{0,0,0,0}}, aI[2] = {{0,0,0,0},{0,0,0,0}};

#pragma unroll
        for (int kt = 0; kt < 9; kt++) {
            if (kt < iters) {
                const int k = kst + kt * 32 + koff;
                f16x8 a0, a1;
                if (kq == 3 && kt == 7) {      // action block (k 1024..1056): read-only, cached
                    a0 = *(const f16x8*)(const void*)actp0;
                    a1 = *(const f16x8*)(const void*)actp1;
                } else {                       // h: memory-side coherent loads
                    a0 = aload(arow0 + k);
                    a1 = aload(arow1 + k);
                }
                f16x8 wr = *(const f16x8*)&Wlds[0][m16][kst + kt * 32 + koff];
                f16x8 wz = *(const f16x8*)&Wlds[1][m16][kst + kt * 32 + koff];
                f16x8 wn = *(const f16x8*)&Wlds[2][m16][kst + kt * 32 + koff];
                aR[0] = MFMA16(a0, wr, aR[0]);  aR[1] = MFMA16(a1, wr, aR[1]);
                aZ[0] = MFMA16(a0, wz, aZ[0]);  aZ[1] = MFMA16(a1, wz, aZ[1]);
                if (kq == 3 && kt == 7) {
                    aI[0] = MFMA16(a0, wn, aI[0]);  aI[1] = MFMA16(a1, wn, aI[1]);
                } else {
                    aN[0] = MFMA16(a0, wn, aN[0]);  aN[1] = MFMA16(a1, wn, aN[1]);
                }
            }
        }

        if (kq != 0) {
#pragma unroll
            for (int sub = 0; sub < 2; sub++) {
                float* d = &RED[bsup][kq - 1][sub][lane][0];
                *(float2*)(d + 0)  = make_float2(aR[sub][0], aR[sub][1]);
                *(float2*)(d + 2)  = make_float2(aR[sub][2], aR[sub][3]);
                *(float2*)(d + 4)  = make_float2(aZ[sub][0], aZ[sub][1]);
                *(float2*)(d + 6)  = make_float2(aZ[sub][2], aZ[sub][3]);
                *(float2*)(d + 8)  = make_float2(aN[sub][0], aN[sub][1]);
                *(float2*)(d + 10) = make_float2(aN[sub][2], aN[sub][3]);
                *(float2*)(d + 12) = make_float2(aI[sub][0], aI[sub][1]);
                *(float2*)(d + 14) = make_float2(aI[sub][2], aI[sub][3]);
            }
        }
        __syncthreads();
        if (kq == 0) {
            u16* orow = outs + (size_t)t * BS * HID;
#pragma unroll
            for (int sub = 0; sub < 2; sub++) {
                float R[4], Z[4], N[4], I[4];
#pragma unroll
                for (int rg = 0; rg < 4; rg++) {
                    R[rg] = aR[sub][rg]; Z[rg] = aZ[sub][rg];
                    N[rg] = aN[sub][rg]; I[rg] = aI[sub][rg];
                }
#pragma unroll
                for (int src = 0; src < 3; src++) {
                    const float* d = &RED[bsup][src][sub][lane][0];
#pragma unroll
                    for (int rg = 0; rg < 4; rg++) {
                        R[rg] += d[rg]; Z[rg] += d[4 + rg];
                        N[rg] += d[8 + rg]; I[rg] += d[12 + rg];
                    }
                }
#pragma unroll
                for (int rg = 0; rg < 4; rg++) {
                    float r = sigm(R[rg] + bir);
                    float z = sigm(Z[rg] + biz);
                    float n = tanhf(I[rg] + bin_ + r * (N[rg] + bh_));
                    float hnew = (1.0f - z) * n + z * hreg[sub][rg];
                    hreg[sub][rg] = hnew;
                    // memory-side coherent store (write-through to IC, no fence needed)
                    __hip_atomic_store(
                        &orow[(size_t)(b0 + bsup * 32 + sub * 16 + quad * 4 + rg) * HID + j],
                        f2h(hnew), __ATOMIC_RELAXED, __HIP_MEMORY_SCOPE_AGENT);
                }
            }
        }

        // ---- grid barrier: NO fences, NO invalidates ----
        __builtin_amdgcn_s_waitcnt(0);         // stores IC-acked before we signal
        __syncthreads();
        if (tid == 0) {
            __hip_atomic_fetch_add(bar, 1u, __ATOMIC_RELAXED, __HIP_MEMORY_SCOPE_AGENT);
            u32 tgt = 256u * (u32)(t + 1);
            while (__hip_atomic_load(bar, __ATOMIC_RELAXED, __HIP_MEMORY_SCOPE_AGENT) < tgt)
                __builtin_amdgcn_s_sleep(2);
        }
        __syncthreads();
    }
}

// ---------------- k_out: out = outs(fp16) @ Wo + bo, MFMA ----------------
__global__ __launch_bounds__(256) void k_out(const u16* __restrict__ outs,
                                             const u16* __restrict__ WoT,
                                             const float* __restrict__ bo,
                                             float* __restrict__ out) {
    __shared__ u16 As[64][40], Bs[64][40];
    const int tid = threadIdx.x;
    const int m0 = blockIdx.x * 64;
    const int w = tid >> 6, lane = tid & 63;
    const int m16 = lane & 15, quad = lane >> 4;
    f32x4 acc[4] = {{0,0,0,0},{0,0,0,0},{0,0,0,0},{0,0,0,0}};

    const int ar = tid >> 2, aq = tid & 3;
    const u16* aptr = outs + (size_t)(m0 + ar) * HID + aq * 8;
    const u16* bptr = WoT + (size_t)ar * HID + aq * 8;
    int4 aR = *(const int4*)(const void*)aptr;
    int4 bR = *(const int4*)(const void*)bptr;

    for (int kt = 0; kt < 32; kt++) {
        __syncthreads();
        *(int4*)(void*)&As[ar][aq * 8] = aR;
        *(int4*)(void*)&Bs[ar][aq * 8] = bR;
        if (kt < 31) {
            aR = *(const int4*)(const void*)(aptr + (kt + 1) * 32);
            bR = *(const int4*)(const void*)(bptr + (kt + 1) * 32);
        }
        __syncthreads();
        f16x8 a = *(const f16x8*)&As[w * 16 + m16][quad * 8];
#pragma unroll
        for (int nt = 0; nt < 4; nt++) {
            f16x8 b = *(const f16x8*)&Bs[nt * 16 + m16][quad * 8];
            acc[nt] = __builtin_amdgcn_mfma_f32_16x16x32_f16(a, b, acc[nt], 0, 0, 0);
        }
    }
    const int mbase = m0 + w * 16 + quad * 4;
#pragma unroll
    for (int nt = 0; nt < 4; nt++) {
        int n = nt * 16 + m16;
        float bov = bo[n];
#pragma unroll
        for (int rg = 0; rg < 4; rg++) {
            int m = mbase + rg;
            int b = m & 255, t = m >> 8;
            out[((size_t)b * TST + t) * OUTD + n] = acc[nt][rg] + bov;
        }
    }
}

extern "C" void kernel_launch(void* const* d_in, const int* in_sizes, int n_in,
                              void* d_out, int out_size, void* d_ws, size_t ws_size,
                              hipStream_t stream) {
    const float* history = (const float*)d_in[0];
    const float* action  = (const float*)d_in[1];
    const float* W_in    = (const float*)d_in[2];
    const float* b_in    = (const float*)d_in[3];
    const float* Wi      = (const float*)d_in[4];
    const float* bi      = (const float*)d_in[5];
    const float* Wh      = (const float*)d_in[6];
    const float* bhn     = (const float*)d_in[7];
    const float* Wo      = (const float*)d_in[8];
    const float* bo      = (const float*)d_in[9];
    float* out = (float*)d_out;

    char* ws = (char*)d_ws;
    float* hbuf0 = (float*)(ws + 0);                    // 1 MB (fp32 h0)
    u16*   h0h   = (u16*)  (ws + (2u << 20));           // 0.5 MB (fp16 h0)
    u16*   Wf    = (u16*)  (ws + (3u << 20));           // 6.33 MB
    u16*   WoT   = (u16*)  (ws + (10u << 20));          // 128 KB
    u16*   acth  = (u16*)  (ws + (11u << 20));          // 1.6 MB
    float* part  = (float*)(ws + (13u << 20));          // 10 MB (13..23 MiB)
    u32*   bar   = (u32*)  (ws + (23u << 20));          // 64 B barrier counter
    u16*   outsb = (u16*)  (ws + (24u << 20));          // 52.4 MB

    (void)hipMemsetAsync(bar, 0, 64, stream);
    k_prep_w<<<dim3(33, 96), 256, 0, stream>>>(Wh, Wi, Wf);
    k_prep_wo<<<256, 256, 0, stream>>>(Wo, WoT);
    k_prep_act<<<800, 256, 0, stream>>>(action, acth);
    k_h0<<<dim3(16, 8, H0_SPLIT), 256, 0, stream>>>(history, W_in, part);
    k_h0red<<<256, 256, 0, stream>>>(part, b_in, hbuf0, h0h);

    {
        const u16* a0 = h0h; const float* a1 = hbuf0; const u16* a2 = acth;
        const u16* a3 = Wf;  const float* a4 = bi;    const float* a5 = bhn;
        u16* a6 = outsb;     u32* a7 = bar;
        void* args[] = {(void*)&a0, (void*)&a1, (void*)&a2, (void*)&a3,
                        (void*)&a4, (void*)&a5, (void*)&a6, (void*)&a7};
        (void)hipLaunchCooperativeKernel((const void*)k_gru, dim3(256), dim3(512),
                                         args, 0, stream);
    }

    k_out<<<400, 256, 0, stream>>>(outsb, WoT, bo, out);
}

// Round 8
// 1100.106 us; speedup vs baseline: 5.2083x; 1.4862x over previous
//
#include <hip/hip_runtime.h>

#define BS   256
#define KIN  8000
#define HID  1024
#define TST  100
#define ACTD 32
#define OUTD 64
#define KTOT 1056            // 1024 (Wh) + 32 (Wi) concatenated K
#define WP   1104            // Wlds row pitch in halfs (552 dw, %32==8 -> uniform banks)
#define HEXCH (16 * 32 * 512)  // one h-exchange buffer: 16 rgrp x 32 kb x 512 u16 (512 KB)

typedef __attribute__((ext_vector_type(8))) _Float16 f16x8;
typedef __attribute__((ext_vector_type(4))) float f32x4;
typedef unsigned short u16;
typedef unsigned int   u32;
typedef unsigned long long u64;

__device__ __forceinline__ u16 f2h(float f) {
    union { _Float16 h; u16 u; } c;
    c.h = (_Float16)f;             // v_cvt_f16_f32, RNE
    return c.u;
}
__device__ __forceinline__ float sigm(float x) { return 1.0f / (1.0f + __expf(-x)); }

#define MFMA16(a, b, c) __builtin_amdgcn_mfma_f32_16x16x32_f16(a, b, c, 0, 0, 0)

// Memory-side coherent 16B load (two relaxed agent-scope u64 atomics).
// With fragment-order layout the 64 lanes of a wave read one DENSE 1 KB chunk.
__device__ __forceinline__ f16x8 aload(const u16* p) {
    union { u64 d[2]; f16x8 v; } u;
    const u64* q = (const u64*)(const void*)p;
    u.d[0] = __hip_atomic_load(q + 0, __ATOMIC_RELAXED, __HIP_MEMORY_SCOPE_AGENT);
    u.d[1] = __hip_atomic_load(q + 1, __ATOMIC_RELAXED, __HIP_MEMORY_SCOPE_AGENT);
    return u.v;
}

// ---------------- P1: WfT[c][k] = fp16(Wh[k][c] | Wi[k-1024][c]) ----------------
__global__ __launch_bounds__(256) void k_prep_w(const float* __restrict__ Wh,
                                                const float* __restrict__ Wi,
                                                u16* __restrict__ Wf) {
    __shared__ float T[32][33];
    const int k0 = blockIdx.x * 32;      // 33 tiles cover k=0..1055
    const int c0 = blockIdx.y * 32;
    const int tid = threadIdx.x;
    {
        int k = tid >> 3, c4 = (tid & 7) * 4;
        int kk = k0 + k;
        const float* src = (kk < HID) ? (Wh + (size_t)kk * 3072 + c0 + c4)
                                      : (Wi + (size_t)(kk - HID) * 3072 + c0 + c4);
        float4 v = *(const float4*)src;
        T[k][c4 + 0] = v.x; T[k][c4 + 1] = v.y; T[k][c4 + 2] = v.z; T[k][c4 + 3] = v.w;
    }
    __syncthreads();
    {
        int c = tid >> 3, k4 = (tid & 7) * 4;
        size_t base = (size_t)(c0 + c) * KTOT + k0 + k4;
#pragma unroll
        for (int j = 0; j < 4; j++) Wf[base + j] = f2h(T[k4 + j][c]);
    }
}

// ---------------- P2: WoT[n][k] = fp16(Wo[k][n]) ----------------
__global__ __launch_bounds__(256) void k_prep_wo(const float* __restrict__ Wo,
                                                 u16* __restrict__ WoT) {
    int idx = blockIdx.x * 256 + threadIdx.x;   // 65536
    int n = idx & 63, k = idx >> 6;
    WoT[(size_t)n * HID + k] = f2h(Wo[(size_t)k * OUTD + n]);
}

// ---------------- P3: action fp32 -> fp16 (layout preserved) ----------------
__global__ __launch_bounds__(256) void k_prep_act(const float* __restrict__ act,
                                                  u16* __restrict__ acth) {
    int i = (blockIdx.x * 256 + threadIdx.x) * 4;
    float4 v = *(const float4*)(act + i);
    ushort4 h = make_ushort4(f2h(v.x), f2h(v.y), f2h(v.z), f2h(v.w));
    *(ushort4*)(acth + i) = h;
}

// ---------------- h0 partial GEMM (fp32, split-K) ----------------
#define H0_SPLIT 10
#define H0_KC    800
__global__ __launch_bounds__(256) void k_h0(const float* __restrict__ x,
                                            const float* __restrict__ Win,
                                            float* __restrict__ part) {
    __shared__ float As[32][33];   // [k][m]
    __shared__ float Bs[32][68];   // [k][n]
    const int n0 = blockIdx.x * 64, m0 = blockIdx.y * 32, s = blockIdx.z;
    const int tid = threadIdx.x;
    const int tm = tid >> 4, tn = tid & 15;
    float acc[2][4] = {};

    const int ar = tid >> 3, ac4 = (tid & 7) * 4;
    int br[2], bn4[2];
#pragma unroll
    for (int i = 0; i < 2; i++) { int e = tid + 256 * i; br[i] = e >> 4; bn4[i] = (e & 15) * 4; }
    const int k0 = s * H0_KC;

    float4 aReg = *(const float4*)(x + (size_t)(m0 + ar) * KIN + k0 + ac4);
    float4 bReg0 = *(const float4*)(Win + (size_t)(k0 + br[0]) * HID + n0 + bn4[0]);
    float4 bReg1 = *(const float4*)(Win + (size_t)(k0 + br[1]) * HID + n0 + bn4[1]);

    for (int it = 0; it < 25; it++) {
        __syncthreads();
        As[ac4 + 0][ar] = aReg.x; As[ac4 + 1][ar] = aReg.y;
        As[ac4 + 2][ar] = aReg.z; As[ac4 + 3][ar] = aReg.w;
        *(float4*)&Bs[br[0]][bn4[0]] = bReg0;
        *(float4*)&Bs[br[1]][bn4[1]] = bReg1;
        if (it < 24) {
            int kn = k0 + (it + 1) * 32;
            aReg  = *(const float4*)(x + (size_t)(m0 + ar) * KIN + kn + ac4);
            bReg0 = *(const float4*)(Win + (size_t)(kn + br[0]) * HID + n0 + bn4[0]);
            bReg1 = *(const float4*)(Win + (size_t)(kn + br[1]) * HID + n0 + bn4[1]);
        }
        __syncthreads();
#pragma unroll
        for (int kk = 0; kk < 32; kk++) {
            float a0 = As[kk][tm * 2], a1 = As[kk][tm * 2 + 1];
            float4 b = *(float4*)&Bs[kk][tn * 4];
            acc[0][0] = fmaf(a0, b.x, acc[0][0]); acc[0][1] = fmaf(a0, b.y, acc[0][1]);
            acc[0][2] = fmaf(a0, b.z, acc[0][2]); acc[0][3] = fmaf(a0, b.w, acc[0][3]);
            acc[1][0] = fmaf(a1, b.x, acc[1][0]); acc[1][1] = fmaf(a1, b.y, acc[1][1]);
            acc[1][2] = fmaf(a1, b.z, acc[1][2]); acc[1][3] = fmaf(a1, b.w, acc[1][3]);
        }
    }
    float* dst = part + (size_t)s * (BS * HID);
#pragma unroll
    for (int i = 0; i < 2; i++) {
        float4 v = make_float4(acc[i][0], acc[i][1], acc[i][2], acc[i][3]);
        *(float4*)(dst + (size_t)(m0 + tm * 2 + i) * HID + n0 + tn * 4) = v;
    }
}

// reduce partials; write fp32 h0 and fragment-order fp16 h0 into hfrag buf 0.
__global__ __launch_bounds__(256) void k_h0red(const float* __restrict__ part,
                                               const float* __restrict__ b_in,
                                               float* __restrict__ h0,
                                               u16* __restrict__ hfrag) {
    int idx = (blockIdx.x * 256 + threadIdx.x) * 4;
    float4 sv = *(const float4*)(part + idx);
#pragma unroll
    for (int p = 1; p < H0_SPLIT; p++) {
        float4 v = *(const float4*)(part + (size_t)p * (BS * HID) + idx);
        sv.x += v.x; sv.y += v.y; sv.z += v.z; sv.w += v.w;
    }
    int n = idx & (HID - 1);
    float4 b = *(const float4*)(b_in + n);
    sv.x = fmaxf(sv.x + b.x, 0.f); sv.y = fmaxf(sv.y + b.y, 0.f);
    sv.z = fmaxf(sv.z + b.z, 0.f); sv.w = fmaxf(sv.w + b.w, 0.f);
    *(float4*)(h0 + idx) = sv;
    int row = idx >> 10;
    float vv[4] = {sv.x, sv.y, sv.z, sv.w};
#pragma unroll
    for (int i = 0; i < 4; i++) {
        int c = n + i;
        int lane = ((c & 31) >> 3) * 16 + (row & 15);
        size_t off = ((size_t)(row >> 4) * 32 + (c >> 5)) * 512 + lane * 8 + (c & 7);
        __hip_atomic_store(hfrag + off, f2h(vv[i]), __ATOMIC_RELAXED, __HIP_MEMORY_SCOPE_AGENT);
    }
}

// ---------------- persistent GRU: all 100 steps in one cooperative launch ----------------
// 256 blocks x 512 thr. Block = 16 j-cols x 64 b-rows; bx: j0=(bx>>2)*16, bt=bx&3.
// Weights (3x16x1056 fp16) staged in LDS once (pitch 1104 halfs = conflict-free).
// h exchange: FRAGMENT-ORDER buffer -- chunk (rgrp,kb) of 1 KB holds exactly the
// 64-lane A-fragment, so uncached IC loads are dense/coalesced. Double-buffered.
// Barrier: per-bt counter (4 disjoint groups of 64 blocks), relaxed atomics only.
__global__ __launch_bounds__(512, 2) void k_gru(const float* __restrict__ h0f,
                                                const u16* __restrict__ acth,
                                                const u16* __restrict__ Wf,
                                                const float* __restrict__ bi,
                                                const float* __restrict__ bhn,
                                                u16* __restrict__ outs,
                                                u16* __restrict__ hfrag,
                                                u32* __restrict__ bars) {
    __shared__ u16 Wlds[3 * 16 * WP];          // 106 KB
    __shared__ float RED[2 * 3 * 2 * 64 * 17]; // 52.2 KB, pitch 17 (odd) = conflict-free

    const int tid = threadIdx.x;
    const int bx = blockIdx.x;
    const int j0 = (bx >> 2) * 16;
    const int bt = bx & 3;
    const int b0 = bt * 64;
    const int w = tid >> 6;
    const int bsup = w >> 2, kq = w & 3;
    const int lane = tid & 63;
    const int m16 = lane & 15, quad = lane >> 4;

    // ---- stage weight slice to LDS (once) ----
    for (int p = 0; p < 13; p++) {
        int c = tid + p * 512;                 // 6336 chunks of 8 halfs
        if (c < 6336) {
            int row = c / 132, kc = (c % 132) * 8;
            int g = row >> 4, jj = row & 15;
            int4 v = *(const int4*)(const void*)(Wf + (size_t)(g * HID + j0 + jj) * KTOT + kc);
            *(int4*)(void*)&Wlds[row * WP + kc] = v;
        }
    }

    // home-wave persistent state
    const int j = j0 + m16;
    float bir = 0, biz = 0, bin_ = 0, bh_ = 0;
    float hreg[2][4] = {};
    if (kq == 0) {
        bir = bi[j]; biz = bi[HID + j]; bin_ = bi[2 * HID + j]; bh_ = bhn[j];
#pragma unroll
        for (int sub = 0; sub < 2; sub++)
#pragma unroll
            for (int rg = 0; rg < 4; rg++)
                hreg[sub][rg] = h0f[(size_t)(b0 + bsup * 32 + sub * 16 + quad * 4 + rg) * HID + j];
    }
    __syncthreads();

    const int kst = kq * 256 + (kq ? 32 : 0);  // {0,288,544,800}
    const int iters = kq ? 8 : 9;
    const int kb0 = kst >> 5;                  // {0,9,17,25}
    const int koff = quad * 8;
    const int rgrp0 = (b0 >> 4) + bsup * 2;    // A rows rgrp0*16.. (sub0), +16 (sub1)
    const int row0 = b0 + bsup * 32 + m16;
    const u16* wbr = &Wlds[(0 * 16 + m16) * WP];
    const u16* wbz = &Wlds[(1 * 16 + m16) * WP];
    const u16* wbn = &Wlds[(2 * 16 + m16) * WP];
    u32* ctr = bars + bt * 32;                 // 128B-strided group counters

    for (int t = 0; t < TST; t++) {
        const u16* pbase = hfrag + (size_t)(t & 1) * HEXCH;
        u16* nbase = hfrag + (size_t)((t + 1) & 1) * HEXCH;
        const u16* actp0 = acth + (size_t)row0 * (TST * ACTD) + t * ACTD + koff;
        const u16* actp1 = actp0 + 16 * (TST * ACTD);

        f32x4 aR[2] = {{0,0,0,0},{0,0,0,0}}, aZ[2] = {{0,0,0,0},{0,0,0,0}};
        f32x4 aN[2] = {{0,0,0,0},{0,0,0,0}}, aI[2] = {{0,0,0,0},{0,0,0,0}};

#pragma unroll
        for (int kt = 0; kt < 9; kt++) {
            if (kt < iters) {
                const int k = kst + kt * 32;
                f16x8 a0, a1;
                if (kq == 3 && kt == 7) {      // action block (read-only, cached)
                    a0 = *(const f16x8*)(const void*)actp0;
                    a1 = *(const f16x8*)(const void*)actp1;
                } else {                       // dense 1KB fragment chunks from IC
                    const int kb = kb0 + kt;
                    a0 = aload(pbase + ((size_t)(rgrp0 * 32 + kb) << 9) + lane * 8);
                    a1 = aload(pbase + ((size_t)((rgrp0 + 1) * 32 + kb) << 9) + lane * 8);
                }
                f16x8 wr = *(const f16x8*)&wbr[k + koff];
                f16x8 wz = *(const f16x8*)&wbz[k + koff];
                f16x8 wn = *(const f16x8*)&wbn[k + koff];
                aR[0] = MFMA16(a0, wr, aR[0]);  aR[1] = MFMA16(a1, wr, aR[1]);
                aZ[0] = MFMA16(a0, wz, aZ[0]);  aZ[1] = MFMA16(a1, wz, aZ[1]);
                if (kq == 3 && kt == 7) {
                    aI[0] = MFMA16(a0, wn, aI[0]);  aI[1] = MFMA16(a1, wn, aI[1]);
                } else {
                    aN[0] = MFMA16(a0, wn, aN[0]);  aN[1] = MFMA16(a1, wn, aN[1]);
                }
            }
        }

        if (kq != 0) {
#pragma unroll
            for (int sub = 0; sub < 2; sub++) {
                float* d = &RED[(((bsup * 3 + (kq - 1)) * 2 + sub) * 64 + lane) * 17];
#pragma unroll
                for (int i = 0; i < 4; i++) {
                    d[i]      = aR[sub][i];
                    d[4 + i]  = aZ[sub][i];
                    d[8 + i]  = aN[sub][i];
                    d[12 + i] = aI[sub][i];
                }
            }
        }
        __syncthreads();
        if (kq == 0) {
            u16* orow = outs + (size_t)t * BS * HID;
#pragma unroll
            for (int sub = 0; sub < 2; sub++) {
                float R[4], Z[4], N[4], I[4];
#pragma unroll
                for (int rg = 0; rg < 4; rg++) {
                    R[rg] = aR[sub][rg]; Z[rg] = aZ[sub][rg];
                    N[rg] = aN[sub][rg]; I[rg] = aI[sub][rg];
                }
#pragma unroll
                for (int src = 0; src < 3; src++) {
                    const float* d = &RED[(((bsup * 3 + src) * 2 + sub) * 64 + lane) * 17];
#pragma unroll
                    for (int rg = 0; rg < 4; rg++) {
                        R[rg] += d[rg]; Z[rg] += d[4 + rg];
                        N[rg] += d[8 + rg]; I[rg] += d[12 + rg];
                    }
                }
                const int rgrp_w = rgrp0 + sub;
                u16* chunk = nbase + ((size_t)(rgrp_w * 32 + (j >> 5)) << 9);
                const int lbase = ((j & 31) >> 3) * 16 + quad * 4;
#pragma unroll
                for (int rg = 0; rg < 4; rg++) {
                    float r = sigm(R[rg] + bir);
                    float z = sigm(Z[rg] + biz);
                    float n = tanhf(I[rg] + bin_ + r * (N[rg] + bh_));
                    float hnew = (1.0f - z) * n + z * hreg[sub][rg];
                    hreg[sub][rg] = hnew;
                    u16 hh = f2h(hnew);
                    // fragment-order exchange store (uncached, memory-side)
                    __hip_atomic_store(chunk + (lbase + rg) * 8 + (j & 7), hh,
                                       __ATOMIC_RELAXED, __HIP_MEMORY_SCOPE_AGENT);
                    // normal cached store for k_out (next dispatch)
                    orow[(size_t)(b0 + bsup * 32 + sub * 16 + quad * 4 + rg) * HID + j] = hh;
                }
            }
        }

        // ---- per-bt group barrier (64 blocks), no fences/invalidates ----
        __builtin_amdgcn_s_waitcnt(0);         // stores acked at coherence point
        __syncthreads();
        if (tid == 0) {
            __hip_atomic_fetch_add(ctr, 1u, __ATOMIC_RELAXED, __HIP_MEMORY_SCOPE_AGENT);
            u32 tgt = 64u * (u32)(t + 1);
            while (__hip_atomic_load(ctr, __ATOMIC_RELAXED, __HIP_MEMORY_SCOPE_AGENT) < tgt)
                __builtin_amdgcn_s_sleep(1);
        }
        __syncthreads();
    }
}

// ---------------- k_out: out = outs(fp16) @ Wo + bo, MFMA ----------------
__global__ __launch_bounds__(256) void k_out(const u16* __restrict__ outs,
                                             const u16* __restrict__ WoT,
                                             const float* __restrict__ bo,
                                             float* __restrict__ out) {
    __shared__ u16 As[64][40], Bs[64][40];
    const int tid = threadIdx.x;
    const int m0 = blockIdx.x * 64;
    const int w = tid >> 6, lane = tid & 63;
    const int m16 = lane & 15, quad = lane >> 4;
    f32x4 acc[4] = {{0,0,0,0},{0,0,0,0},{0,0,0,0},{0,0,0,0}};

    const int ar = tid >> 2, aq = tid & 3;
    const u16* aptr = outs + (size_t)(m0 + ar) * HID + aq * 8;
    const u16* bptr = WoT + (size_t)ar * HID + aq * 8;
    int4 aR = *(const int4*)(const void*)aptr;
    int4 bR = *(const int4*)(const void*)bptr;

    for (int kt = 0; kt < 32; kt++) {
        __syncthreads();
        *(int4*)(void*)&As[ar][aq * 8] = aR;
        *(int4*)(void*)&Bs[ar][aq * 8] = bR;
        if (kt < 31) {
            aR = *(const int4*)(const void*)(aptr + (kt + 1) * 32);
            bR = *(const int4*)(const void*)(bptr + (kt + 1) * 32);
        }
        __syncthreads();
        f16x8 a = *(const f16x8*)&As[w * 16 + m16][quad * 8];
#pragma unroll
        for (int nt = 0; nt < 4; nt++) {
            f16x8 b = *(const f16x8*)&Bs[nt * 16 + m16][quad * 8];
            acc[nt] = __builtin_amdgcn_mfma_f32_16x16x32_f16(a, b, acc[nt], 0, 0, 0);
        }
    }
    const int mbase = m0 + w * 16 + quad * 4;
#pragma unroll
    for (int nt = 0; nt < 4; nt++) {
        int n = nt * 16 + m16;
        float bov = bo[n];
#pragma unroll
        for (int rg = 0; rg < 4; rg++) {
            int m = mbase + rg;
            int b = m & 255, t = m >> 8;
            out[((size_t)b * TST + t) * OUTD + n] = acc[nt][rg] + bov;
        }
    }
}

extern "C" void kernel_launch(void* const* d_in, const int* in_sizes, int n_in,
                              void* d_out, int out_size, void* d_ws, size_t ws_size,
                              hipStream_t stream) {
    const float* history = (const float*)d_in[0];
    const float* action  = (const float*)d_in[1];
    const float* W_in    = (const float*)d_in[2];
    const float* b_in    = (const float*)d_in[3];
    const float* Wi      = (const float*)d_in[4];
    const float* bi      = (const float*)d_in[5];
    const float* Wh      = (const float*)d_in[6];
    const float* bhn     = (const float*)d_in[7];
    const float* Wo      = (const float*)d_in[8];
    const float* bo      = (const float*)d_in[9];
    float* out = (float*)d_out;

    char* ws = (char*)d_ws;
    float* hbuf0 = (float*)(ws + 0);                    // 1 MB (fp32 h0)
    u16*   Wf    = (u16*)  (ws + (3u << 20));           // 6.33 MB
    u16*   WoT   = (u16*)  (ws + (10u << 20));          // 128 KB
    u16*   acth  = (u16*)  (ws + (11u << 20));          // 1.6 MB
    float* part  = (float*)(ws + (13u << 20));          // 10 MB (13..23 MiB)
    u32*   bars  = (u32*)  (ws + (23u << 20));          // 512 B group counters
    u16*   outsb = (u16*)  (ws + (24u << 20));          // 52.4 MB (24..76.4 MiB)
    u16*   hfrag = (u16*)  (ws + (77u << 20));          // 2 x 512 KB exchange buffers

    (void)hipMemsetAsync(bars, 0, 512, stream);
    k_prep_w<<<dim3(33, 96), 256, 0, stream>>>(Wh, Wi, Wf);
    k_prep_wo<<<256, 256, 0, stream>>>(Wo, WoT);
    k_prep_act<<<800, 256, 0, stream>>>(action, acth);
    k_h0<<<dim3(16, 8, H0_SPLIT), 256, 0, stream>>>(history, W_in, part);
    k_h0red<<<256, 256, 0, stream>>>(part, b_in, hbuf0, hfrag);

    {
        const float* a0 = hbuf0; const u16* a1 = acth; const u16* a2 = Wf;
        const float* a3 = bi;    const float* a4 = bhn;
        u16* a5 = outsb;         u16* a6 = hfrag;       u32* a7 = bars;
        void* args[] = {(void*)&a0, (void*)&a1, (void*)&a2, (void*)&a3,
                        (void*)&a4, (void*)&a5, (void*)&a6, (void*)&a7};
        (void)hipLaunchCooperativeKernel((const void*)k_gru, dim3(256), dim3(512),
                                         args, 0, stream);
    }

    k_out<<<400, 256, 0, stream>>>(outsb, WoT, bo, out);
}

// Round 10
// 1001.928 us; speedup vs baseline: 5.7187x; 1.0980x over previous
//
#include <hip/hip_runtime.h>

#define BS   256
#define HID  1024
#define KIN  8000
#define TST  100
#define ACTD 32
#define OUTD 64
#define KTOT 1056            // 1024 (Wh) + 32 (Wi) concatenated K
#define WP   1104            // Wlds row pitch in halfs (552 dw, %32==8 -> uniform banks)
#define HEXCH (16 * 32 * 512)  // one h-exchange buffer: 16 rgrp x 32 kb x 512 u16 (512 KB)

typedef __attribute__((ext_vector_type(8))) _Float16 f16x8;
typedef __attribute__((ext_vector_type(4))) float f32x4;
typedef unsigned short u16;
typedef unsigned int   u32;
typedef unsigned long long u64;

__device__ __forceinline__ u16 f2h(float f) {
    union { _Float16 h; u16 u; } c;
    c.h = (_Float16)f;             // v_cvt_f16_f32, RNE
    return c.u;
}
__device__ __forceinline__ float sigm(float x) { return 1.0f / (1.0f + __expf(-x)); }

#define MFMA16(a, b, c) __builtin_amdgcn_mfma_f32_16x16x32_f16(a, b, c, 0, 0, 0)

// Memory-side coherent 16B load (two relaxed agent-scope u64 atomics).
__device__ __forceinline__ f16x8 aload(const u16* p) {
    union { u64 d[2]; f16x8 v; } u;
    const u64* q = (const u64*)(const void*)p;
    u.d[0] = __hip_atomic_load(q + 0, __ATOMIC_RELAXED, __HIP_MEMORY_SCOPE_AGENT);
    u.d[1] = __hip_atomic_load(q + 1, __ATOMIC_RELAXED, __HIP_MEMORY_SCOPE_AGENT);
    return u.v;
}

// ---------------- P1: WfT[c][k] = fp16(Wh[k][c] | Wi[k-1024][c]) ----------------
__global__ __launch_bounds__(256) void k_prep_w(const float* __restrict__ Wh,
                                                const float* __restrict__ Wi,
                                                u16* __restrict__ Wf) {
    __shared__ float T[32][33];
    const int k0 = blockIdx.x * 32;      // 33 tiles cover k=0..1055
    const int c0 = blockIdx.y * 32;
    const int tid = threadIdx.x;
    {
        int k = tid >> 3, c4 = (tid & 7) * 4;
        int kk = k0 + k;
        const float* src = (kk < HID) ? (Wh + (size_t)kk * 3072 + c0 + c4)
                                      : (Wi + (size_t)(kk - HID) * 3072 + c0 + c4);
        float4 v = *(const float4*)src;
        T[k][c4 + 0] = v.x; T[k][c4 + 1] = v.y; T[k][c4 + 2] = v.z; T[k][c4 + 3] = v.w;
    }
    __syncthreads();
    {
        int c = tid >> 3, k4 = (tid & 7) * 4;
        size_t base = (size_t)(c0 + c) * KTOT + k0 + k4;
#pragma unroll
        for (int j = 0; j < 4; j++) Wf[base + j] = f2h(T[k4 + j][c]);
    }
}

// ---------------- P2: WoT[n][k] = fp16(Wo[k][n]) ----------------
__global__ __launch_bounds__(256) void k_prep_wo(const float* __restrict__ Wo,
                                                 u16* __restrict__ WoT) {
    int idx = blockIdx.x * 256 + threadIdx.x;   // 65536
    int n = idx & 63, k = idx >> 6;
    WoT[(size_t)n * HID + k] = f2h(Wo[(size_t)k * OUTD + n]);
}

// ---------------- P3: action fp32 -> fp16 (layout preserved) ----------------
__global__ __launch_bounds__(256) void k_prep_act(const float* __restrict__ act,
                                                  u16* __restrict__ acth) {
    int i = (blockIdx.x * 256 + threadIdx.x) * 4;
    float4 v = *(const float4*)(act + i);
    ushort4 h = make_ushort4(f2h(v.x), f2h(v.y), f2h(v.z), f2h(v.w));
    *(ushort4*)(acth + i) = h;
}

// ---------------- h0 partial GEMM (fp32, split-K) ----------------
#define H0_SPLIT 10
#define H0_KC    800
__global__ __launch_bounds__(256) void k_h0(const float* __restrict__ x,
                                            const float* __restrict__ Win,
                                            float* __restrict__ part) {
    __shared__ float As[32][33];   // [k][m]
    __shared__ float Bs[32][68];   // [k][n]
    const int n0 = blockIdx.x * 64, m0 = blockIdx.y * 32, s = blockIdx.z;
    const int tid = threadIdx.x;
    const int tm = tid >> 4, tn = tid & 15;
    float acc[2][4] = {};

    const int ar = tid >> 3, ac4 = (tid & 7) * 4;
    int br[2], bn4[2];
#pragma unroll
    for (int i = 0; i < 2; i++) { int e = tid + 256 * i; br[i] = e >> 4; bn4[i] = (e & 15) * 4; }
    const int k0 = s * H0_KC;

    float4 aReg = *(const float4*)(x + (size_t)(m0 + ar) * KIN + k0 + ac4);
    float4 bReg0 = *(const float4*)(Win + (size_t)(k0 + br[0]) * HID + n0 + bn4[0]);
    float4 bReg1 = *(const float4*)(Win + (size_t)(k0 + br[1]) * HID + n0 + bn4[1]);

    for (int it = 0; it < 25; it++) {
        __syncthreads();
        As[ac4 + 0][ar] = aReg.x; As[ac4 + 1][ar] = aReg.y;
        As[ac4 + 2][ar] = aReg.z; As[ac4 + 3][ar] = aReg.w;
        *(float4*)&Bs[br[0]][bn4[0]] = bReg0;
        *(float4*)&Bs[br[1]][bn4[1]] = bReg1;
        if (it < 24) {
            int kn = k0 + (it + 1) * 32;
            aReg  = *(const float4*)(x + (size_t)(m0 + ar) * KIN + kn + ac4);
            bReg0 = *(const float4*)(Win + (size_t)(kn + br[0]) * HID + n0 + bn4[0]);
            bReg1 = *(const float4*)(Win + (size_t)(kn + br[1]) * HID + n0 + bn4[1]);
        }
        __syncthreads();
#pragma unroll
        for (int kk = 0; kk < 32; kk++) {
            float a0 = As[kk][tm * 2], a1 = As[kk][tm * 2 + 1];
            float4 b = *(float4*)&Bs[kk][tn * 4];
            acc[0][0] = fmaf(a0, b.x, acc[0][0]); acc[0][1] = fmaf(a0, b.y, acc[0][1]);
            acc[0][2] = fmaf(a0, b.z, acc[0][2]); acc[0][3] = fmaf(a0, b.w, acc[0][3]);
            acc[1][0] = fmaf(a1, b.x, acc[1][0]); acc[1][1] = fmaf(a1, b.y, acc[1][1]);
            acc[1][2] = fmaf(a1, b.z, acc[1][2]); acc[1][3] = fmaf(a1, b.w, acc[1][3]);
        }
    }
    float* dst = part + (size_t)s * (BS * HID);
#pragma unroll
    for (int i = 0; i < 2; i++) {
        float4 v = make_float4(acc[i][0], acc[i][1], acc[i][2], acc[i][3]);
        *(float4*)(dst + (size_t)(m0 + tm * 2 + i) * HID + n0 + tn * 4) = v;
    }
}

// reduce partials; write fp32 h0 and fragment-order fp16 h0 into hfrag buf 0.
__global__ __launch_bounds__(256) void k_h0red(const float* __restrict__ part,
                                               const float* __restrict__ b_in,
                                               float* __restrict__ h0,
                                               u16* __restrict__ hfrag) {
    int idx = (blockIdx.x * 256 + threadIdx.x) * 4;
    float4 sv = *(const float4*)(part + idx);
#pragma unroll
    for (int p = 1; p < H0_SPLIT; p++) {
        float4 v = *(const float4*)(part + (size_t)p * (BS * HID) + idx);
        sv.x += v.x; sv.y += v.y; sv.z += v.z; sv.w += v.w;
    }
    int n = idx & (HID - 1);
    float4 b = *(const float4*)(b_in + n);
    sv.x = fmaxf(sv.x + b.x, 0.f); sv.y = fmaxf(sv.y + b.y, 0.f);
    sv.z = fmaxf(sv.z + b.z, 0.f); sv.w = fmaxf(sv.w + b.w, 0.f);
    *(float4*)(h0 + idx) = sv;
    int row = idx >> 10;
    float vv[4] = {sv.x, sv.y, sv.z, sv.w};
#pragma unroll
    for (int i = 0; i < 4; i++) {
        int c = n + i;
        int lane = ((c & 31) >> 3) * 16 + (row & 15);
        size_t off = ((size_t)(row >> 4) * 32 + (c >> 5)) * 512 + lane * 8 + (c & 7);
        __hip_atomic_store(hfrag + off, f2h(vv[i]), __ATOMIC_RELAXED, __HIP_MEMORY_SCOPE_AGENT);
    }
}

// ---------------- persistent GRU: all 100 steps in one cooperative launch ----------------
// 256 blocks x 512 thr. Block = 16 j-cols x 64 b-rows; bx: j0=(bx>>2)*16, bt=bx&3.
// Weights in LDS once. h exchange in fragment order (dense 1KB chunks).
// (1) ALL uncached A-loads hoisted to a prologue (atomics are compiler-ordered ->
//     must be issued back-to-back to overlap their latency);
// (2) h stores staged through LDS, flushed as 256 dense u64s (full 2 KB of HST --
//     R9 bug was flushing only 128 u64s = half of HST).
__global__ __launch_bounds__(512, 1) void k_gru(const float* __restrict__ h0f,
                                                const u16* __restrict__ acth,
                                                const u16* __restrict__ Wf,
                                                const float* __restrict__ bi,
                                                const float* __restrict__ bhn,
                                                u16* __restrict__ outs,
                                                u16* __restrict__ hfrag,
                                                u32* __restrict__ bars) {
    __shared__ u16 Wlds[3 * 16 * WP];          // 106 KB
    __shared__ float RED[2 * 3 * 2 * 64 * 17]; // 52.2 KB, pitch 17 = conflict-free
    __shared__ u16 HST[4 * 256];               // 2 KB h-store staging (rgidx x 256 u16)

    const int tid = threadIdx.x;
    const int bx = blockIdx.x;
    const int j0 = (bx >> 2) * 16;
    const int bt = bx & 3;
    const int b0 = bt * 64;
    const int w = tid >> 6;
    const int bsup = w >> 2, kq = w & 3;
    const int lane = tid & 63;
    const int m16 = lane & 15, quad = lane >> 4;

    // ---- stage weight slice to LDS (once) ----
    for (int p = 0; p < 13; p++) {
        int c = tid + p * 512;                 // 6336 chunks of 8 halfs
        if (c < 6336) {
            int row = c / 132, kc = (c % 132) * 8;
            int g = row >> 4, jj = row & 15;
            int4 v = *(const int4*)(const void*)(Wf + (size_t)(g * HID + j0 + jj) * KTOT + kc);
            *(int4*)(void*)&Wlds[row * WP + kc] = v;
        }
    }

    // home-wave persistent state
    const int j = j0 + m16;
    float bir = 0, biz = 0, bin_ = 0, bh_ = 0;
    float hreg[2][4] = {};
    if (kq == 0) {
        bir = bi[j]; biz = bi[HID + j]; bin_ = bi[2 * HID + j]; bh_ = bhn[j];
#pragma unroll
        for (int sub = 0; sub < 2; sub++)
#pragma unroll
            for (int rg = 0; rg < 4; rg++)
                hreg[sub][rg] = h0f[(size_t)(b0 + bsup * 32 + sub * 16 + quad * 4 + rg) * HID + j];
    }
    __syncthreads();

    const int kst = kq * 256 + (kq ? 32 : 0);  // {0,288,544,800}
    const int iters = kq ? 8 : 9;
    const int kb0 = kst >> 5;                  // {0,9,17,25}
    const int koff = quad * 8;
    const int rgb = b0 >> 4;                   // block's first rgrp
    const int rgrp0 = rgb + bsup * 2;          // this wave's A rgrp (sub0)
    const int row0 = b0 + bsup * 32 + m16;
    const u16* wbr = &Wlds[(0 * 16 + m16) * WP];
    const u16* wbz = &Wlds[(1 * 16 + m16) * WP];
    const u16* wbn = &Wlds[(2 * 16 + m16) * WP];
    const int jb = j0 >> 5;                    // k-chunk col index of this j-tile
    const int halfbase = (j0 & 16) ? 256 : 0;  // u16 offset of our 512B half-chunk
    u32* ctr = bars + bt * 32;                 // 128B-strided group counters

    // dense h-store map: threads 0..255 each write one u64 (4 u16) = full 2 KB HST
    const int srg = tid >> 6, sq = tid & 63;   // rgidx (0..3), u64-within-half (0..63)

    for (int t = 0; t < TST; t++) {
        const u16* pbase = hfrag + (size_t)(t & 1) * HEXCH;
        u16* nbase = hfrag + (size_t)((t + 1) & 1) * HEXCH;
        const u16* actp0 = acth + (size_t)row0 * (TST * ACTD) + t * ACTD + koff;
        const u16* actp1 = actp0 + 16 * (TST * ACTD);

        // ---- PROLOGUE: issue ALL A-loads back-to-back (latency overlap) ----
        f16x8 a0s[9], a1s[9];
#pragma unroll
        for (int kt = 0; kt < 9; kt++) {
            if (kt < iters) {
                if (kq == 3 && kt == 7) {      // action block (read-only, cached)
                    a0s[kt] = *(const f16x8*)(const void*)actp0;
                    a1s[kt] = *(const f16x8*)(const void*)actp1;
                } else {                       // dense 1KB fragment chunks, uncached
                    const int kb = kb0 + kt;
                    a0s[kt] = aload(pbase + ((size_t)(rgrp0 * 32 + kb) << 9) + lane * 8);
                    a1s[kt] = aload(pbase + ((size_t)((rgrp0 + 1) * 32 + kb) << 9) + lane * 8);
                }
            }
        }

        f32x4 aR[2] = {{0,0,0,0},{0,0,0,0}}, aZ[2] = {{0,0,0,0},{0,0,0,0}};
        f32x4 aN[2] = {{0,0,0,0},{0,0,0,0}}, aI[2] = {{0,0,0,0},{0,0,0,0}};

#pragma unroll
        for (int kt = 0; kt < 9; kt++) {
            if (kt < iters) {
                const int k = kst + kt * 32;
                f16x8 a0 = a0s[kt], a1 = a1s[kt];
                f16x8 wr = *(const f16x8*)&wbr[k + koff];
                f16x8 wz = *(const f16x8*)&wbz[k + koff];
                f16x8 wn = *(const f16x8*)&wbn[k + koff];
                aR[0] = MFMA16(a0, wr, aR[0]);  aR[1] = MFMA16(a1, wr, aR[1]);
                aZ[0] = MFMA16(a0, wz, aZ[0]);  aZ[1] = MFMA16(a1, wz, aZ[1]);
                if (kq == 3 && kt == 7) {
                    aI[0] = MFMA16(a0, wn, aI[0]);  aI[1] = MFMA16(a1, wn, aI[1]);
                } else {
                    aN[0] = MFMA16(a0, wn, aN[0]);  aN[1] = MFMA16(a1, wn, aN[1]);
                }
            }
        }

        if (kq != 0) {
#pragma unroll
            for (int sub = 0; sub < 2; sub++) {
                float* d = &RED[(((bsup * 3 + (kq - 1)) * 2 + sub) * 64 + lane) * 17];
#pragma unroll
                for (int i = 0; i < 4; i++) {
                    d[i]      = aR[sub][i];
                    d[4 + i]  = aZ[sub][i];
                    d[8 + i]  = aN[sub][i];
                    d[12 + i] = aI[sub][i];
                }
            }
        }
        __syncthreads();
        if (kq == 0) {
            u16* orow = outs + (size_t)t * BS * HID;
#pragma unroll
            for (int sub = 0; sub < 2; sub++) {
                float R[4], Z[4], N[4], I[4];
#pragma unroll
                for (int rg = 0; rg < 4; rg++) {
                    R[rg] = aR[sub][rg]; Z[rg] = aZ[sub][rg];
                    N[rg] = aN[sub][rg]; I[rg] = aI[sub][rg];
                }
#pragma unroll
                for (int src = 0; src < 3; src++) {
                    const float* d = &RED[(((bsup * 3 + src) * 2 + sub) * 64 + lane) * 17];
#pragma unroll
                    for (int rg = 0; rg < 4; rg++) {
                        R[rg] += d[rg]; Z[rg] += d[4 + rg];
                        N[rg] += d[8 + rg]; I[rg] += d[12 + rg];
                    }
                }
                const int rgidx = bsup * 2 + sub;
                const int lh = ((j & 15) >> 3) * 16 + quad * 4;   // lane-in-half base
#pragma unroll
                for (int rg = 0; rg < 4; rg++) {
                    float r = sigm(R[rg] + bir);
                    float z = sigm(Z[rg] + biz);
                    float n = tanhf(I[rg] + bin_ + r * (N[rg] + bh_));
                    float hnew = (1.0f - z) * n + z * hreg[sub][rg];
                    hreg[sub][rg] = hnew;
                    u16 hh = f2h(hnew);
                    HST[rgidx * 256 + (lh + rg) * 8 + (j & 7)] = hh;     // LDS scatter
                    orow[(size_t)(b0 + bsup * 32 + sub * 16 + quad * 4 + rg) * HID + j] = hh;
                }
            }
        }
        __syncthreads();
        // ---- dense coalesced h-exchange store (threads 0..255, one u64 each) ----
        if (tid < 256) {
            u64 v = *(const u64*)(const void*)&HST[srg * 256 + sq * 4];
            u64* dst = (u64*)(void*)(nbase + (((size_t)(rgb + srg) * 32 + jb) << 9)
                                     + halfbase + sq * 4);
            __hip_atomic_store(dst, v, __ATOMIC_RELAXED, __HIP_MEMORY_SCOPE_AGENT);
        }

        // ---- per-bt group barrier (64 blocks), no fences/invalidates ----
        __builtin_amdgcn_s_waitcnt(0);         // stores acked at coherence point
        __syncthreads();
        if (tid == 0) {
            __hip_atomic_fetch_add(ctr, 1u, __ATOMIC_RELAXED, __HIP_MEMORY_SCOPE_AGENT);
            u32 tgt = 64u * (u32)(t + 1);
            while (__hip_atomic_load(ctr, __ATOMIC_RELAXED, __HIP_MEMORY_SCOPE_AGENT) < tgt)
                __builtin_amdgcn_s_sleep(1);
        }
        __syncthreads();
    }
}

// ---------------- k_out: out = outs(fp16) @ Wo + bo, MFMA ----------------
__global__ __launch_bounds__(256) void k_out(const u16* __restrict__ outs,
                                             const u16* __restrict__ WoT,
                                             const float* __restrict__ bo,
                                             float* __restrict__ out) {
    __shared__ u16 As[64][40], Bs[64][40];
    const int tid = threadIdx.x;
    const int m0 = blockIdx.x * 64;
    const int w = tid >> 6, lane = tid & 63;
    const int m16 = lane & 15, quad = lane >> 4;
    f32x4 acc[4] = {{0,0,0,0},{0,0,0,0},{0,0,0,0},{0,0,0,0}};

    const int ar = tid >> 2, aq = tid & 3;
    const u16* aptr = outs + (size_t)(m0 + ar) * HID + aq * 8;
    const u16* bptr = WoT + (size_t)ar * HID + aq * 8;
    int4 aR = *(const int4*)(const void*)aptr;
    int4 bR = *(const int4*)(const void*)bptr;

    for (int kt = 0; kt < 32; kt++) {
        __syncthreads();
        *(int4*)(void*)&As[ar][aq * 8] = aR;
        *(int4*)(void*)&Bs[ar][aq * 8] = bR;
        if (kt < 31) {
            aR = *(const int4*)(const void*)(aptr + (kt + 1) * 32);
            bR = *(const int4*)(const void*)(bptr + (kt + 1) * 32);
        }
        __syncthreads();
        f16x8 a = *(const f16x8*)&As[w * 16 + m16][quad * 8];
#pragma unroll
        for (int nt = 0; nt < 4; nt++) {
            f16x8 b = *(const f16x8*)&Bs[nt * 16 + m16][quad * 8];
            acc[nt] = __builtin_amdgcn_mfma_f32_16x16x32_f16(a, b, acc[nt], 0, 0, 0);
        }
    }
    const int mbase = m0 + w * 16 + quad * 4;
#pragma unroll
    for (int nt = 0; nt < 4; nt++) {
        int n = nt * 16 + m16;
        float bov = bo[n];
#pragma unroll
        for (int rg = 0; rg < 4; rg++) {
            int m = mbase + rg;
            int b = m & 255, t = m >> 8;
            out[((size_t)b * TST + t) * OUTD + n] = acc[nt][rg] + bov;
        }
    }
}

extern "C" void kernel_launch(void* const* d_in, const int* in_sizes, int n_in,
                              void* d_out, int out_size, void* d_ws, size_t ws_size,
                              hipStream_t stream) {
    const float* history = (const float*)d_in[0];
    const float* action  = (const float*)d_in[1];
    const float* W_in    = (const float*)d_in[2];
    const float* b_in    = (const float*)d_in[3];
    const float* Wi      = (const float*)d_in[4];
    const float* bi      = (const float*)d_in[5];
    const float* Wh      = (const float*)d_in[6];
    const float* bhn     = (const float*)d_in[7];
    const float* Wo      = (const float*)d_in[8];
    const float* bo      = (const float*)d_in[9];
    float* out = (float*)d_out;

    char* ws = (char*)d_ws;
    float* hbuf0 = (float*)(ws + 0);                    // 1 MB (fp32 h0)
    u16*   Wf    = (u16*)  (ws + (3u << 20));           // 6.33 MB
    u16*   WoT   = (u16*)  (ws + (10u << 20));          // 128 KB
    u16*   acth  = (u16*)  (ws + (11u << 20));          // 1.6 MB
    float* part  = (float*)(ws + (13u << 20));          // 10 MB (13..23 MiB)
    u32*   bars  = (u32*)  (ws + (23u << 20));          // 512 B group counters
    u16*   outsb = (u16*)  (ws + (24u << 20));          // 52.4 MB (24..76.4 MiB)
    u16*   hfrag = (u16*)  (ws + (77u << 20));          // 2 x 512 KB exchange buffers

    (void)hipMemsetAsync(bars, 0, 512, stream);
    k_prep_w<<<dim3(33, 96), 256, 0, stream>>>(Wh, Wi, Wf);
    k_prep_wo<<<256, 256, 0, stream>>>(Wo, WoT);
    k_prep_act<<<800, 256, 0, stream>>>(action, acth);
    k_h0<<<dim3(16, 8, H0_SPLIT), 256, 0, stream>>>(history, W_in, part);
    k_h0red<<<256, 256, 0, stream>>>(part, b_in, hbuf0, hfrag);

    {
        const float* a0 = hbuf0; const u16* a1 = acth; const u16* a2 = Wf;
        const float* a3 = bi;    const float* a4 = bhn;
        u16* a5 = outsb;         u16* a6 = hfrag;       u32* a7 = bars;
        void* args[] = {(void*)&a0, (void*)&a1, (void*)&a2, (void*)&a3,
                        (void*)&a4, (void*)&a5, (void*)&a6, (void*)&a7};
        (void)hipLaunchCooperativeKernel((const void*)k_gru, dim3(256), dim3(512),
                                         args, 0, stream);
    }

    k_out<<<400, 256, 0, stream>>>(outsb, WoT, bo, out);
}